// Round 5
// baseline (70367.059 us; speedup 1.0000x reference)
//
#include <hip/hip_runtime.h>
#include <hip/hip_bf16.h>

// ContinuousRecurrentCore (liquid-time-constant net) on MI355X.
//
// Per (step,layer): ONE fused bf16x3 MFMA GEMM producing both tau_pre and
// forcing_pre, + register-local epilogue (sigmoid/tanh/state update/delta max).
// fp32 emulated via bf16 hi/lo split: A*W ~= Ahi*Whi + Alo*Whi + Ahi*Wlo
// (dropped lo*lo term ~2e-6 abs), expressed as a single K=6144 bf16 GEMM
// (6 passes over 4 STORED weight K-blocks — hi blocks are reused by the lo-A
// passes instead of being stored twice).
// N=2048 packs tau/forc columns in alternating 16-wide blocks so each
// thread's MFMA C-fragments hold matching (tau, forc) pairs for the same
// output element -> no cross-lane epilogue.
// Device-side early-exit preserves reference freeze/t_conv semantics.
//
// R4 crash fix: previous round carved 369MB out of d_ws with no size check;
// bench aborted (GPU memory fault pattern). ALL buffers now live in static
// __device__ globals (module-load allocation; no hipMalloc, graph-safe).
// Every buffer is fully rewritten each call -> no cross-call state.

typedef __attribute__((ext_vector_type(8))) short bf16x8s;
typedef __attribute__((ext_vector_type(4))) float f32x4;

constexpr int HD = 1024;       // hidden dim
constexpr int MR = 8192;       // B*S rows
constexpr int NLAYER = 4;
constexpr int MAXT = 50;
constexpr float DTC = 0.05f;
constexpr float EPS_TAU_C = 1e-6f;
constexpr float EPS_CONV_C = 1e-3f;

// packed GEMM dims
constexpr int KSTORE = 4096;   // 4 stored K-blocks of 1024: [Wx_hi, Wh_hi, Wx_lo, Wh_lo]
constexpr int NPACK = 2048;    // tau/forc interleaved at 16-col granularity
constexpr size_t WP_PER_LAYER = (size_t)(KSTORE / 64) * 16 * 128 * 64;  // 8.39M elem
constexpr size_t HN = (size_t)MR * HD;      // elements in one state array

struct Ctrl {
  unsigned int done;
  int t_conv;
  unsigned int delta[MAXT];
};

// ---------------------------------------------------------- static workspace
__device__ __align__(16) __hip_bfloat16 g_Wp[NLAYER * WP_PER_LAYER];   // 67MB
__device__ __align__(16) __hip_bfloat16 g_xhi[HN];                     // 16.8MB
__device__ __align__(16) __hip_bfloat16 g_xlo[HN];                     // 16.8MB
__device__ __align__(16) __hip_bfloat16 g_h_hi[2 * NLAYER * HN];       // 134MB [par][layer][elem]
__device__ __align__(16) __hip_bfloat16 g_h_lo[2 * NLAYER * HN];       // 134MB
__device__ float g_btau[NLAYER * HD];
__device__ float g_bforc[NLAYER * HD];
__device__ Ctrl g_ctrl;

__device__ __forceinline__ void gload_lds16(const __hip_bfloat16* g, __hip_bfloat16* lds) {
  __builtin_amdgcn_global_load_lds(
      (const __attribute__((address_space(1))) unsigned int*)g,
      (__attribute__((address_space(3))) unsigned int*)lds, 16, 0, 0);
}

// Branch-free tanh: t = e^{-2|x|} in (0,1] (never overflows),
// tanh = sign(x)*(1-t)/(1+t). ~1e-6 abs error, well below the bf16x3 GEMM
// error (~1e-5) that bounds trajectory fidelity. Replaces branchy ocml tanhf.
__device__ __forceinline__ float fast_tanh(float x) {
  float t = __expf(-2.0f * fabsf(x));
  float r = __fdividef(1.0f - t, 1.0f + t);
  return copysignf(r, x);
}

// ---------------------------------------------------------------- weight pack
// g_Wp layout: [layer][kt(64)][nt(16)][nn(128)][kk(64)] bf16 — B-tiles are
// contiguous 16KB blobs, LDS image is [n][k] (k contiguous per column).
// n-packing: b=n>>4 (16-col blocks), j=(b>>1)*16+(n&15); b even=tau, odd=forc.
// k-storage: kb=kg>>10 -> [Wx_hi, Wh_hi, Wx_lo, Wh_lo].
// GEMM runs 6 passes pairing (A-source, stored block):
//   p0:(x_hi,Wx_hi) p1:(h_hi,Wh_hi) p2:(x_lo,Wx_hi) p3:(h_lo,Wh_hi)
//   p4:(x_hi,Wx_lo) p5:(h_hi,Wh_lo)  -> all 3 bf16x3 terms per operand.
__global__ void pack_weights(const float* __restrict__ w_state,
                             const float* __restrict__ w_input,
                             const float* __restrict__ w_tau,
                             const float* __restrict__ b_state,
                             const float* __restrict__ b_input,
                             const float* __restrict__ b_tau) {
  size_t idx = (size_t)blockIdx.x * blockDim.x + threadIdx.x;
  if (idx < (size_t)NLAYER * HD) {
    int l = (int)(idx >> 10), jj = (int)(idx & 1023);
    g_btau[idx]  = b_tau[l * HD + jj];
    g_bforc[idx] = b_state[l * HD + jj] + b_input[l * HD + jj];
  }
  const size_t total = (size_t)NLAYER * KSTORE * NPACK;
  if (idx >= total) return;
  int kk = (int)(idx & 63);  size_t r = idx >> 6;
  int nn = (int)(r & 127);   r >>= 7;
  int nt = (int)(r & 15);    r >>= 4;
  int kt = (int)(r & 63);    // KSTORE/64 = 64 k-tiles
  int layer = (int)(r >> 6);
  int kg = kt * 64 + kk;
  int kb = kg >> 10;         // 0..3 stored blocks
  int k  = kg & 1023;
  int n  = nt * 128 + nn;
  int b  = n >> 4;
  int j  = (b >> 1) * 16 + (n & 15);
  bool is_tau = (b & 1) == 0;
  bool is_h   = (kb & 1) != 0;
  bool is_lo  = kb >= 2;
  float wv;
  if (is_tau) wv = w_tau[(size_t)layer * HD * 2 * HD + (size_t)j * 2 * HD + (is_h ? HD + k : k)];
  else        wv = is_h ? w_state[(size_t)layer * HD * HD + (size_t)j * HD + k]
                        : w_input[(size_t)layer * HD * HD + (size_t)j * HD + k];
  float hi = __bfloat162float(__float2bfloat16(wv));
  g_Wp[idx] = __float2bfloat16(is_lo ? (wv - hi) : wv);
}

// ------------------------------------------------------------------- x split
__global__ void split_x(const float* __restrict__ x) {
  size_t i = (size_t)blockIdx.x * blockDim.x + threadIdx.x;
  if (i >= HN) return;
  float v = x[i];
  __hip_bfloat16 h16 = __float2bfloat16(v);
  g_xhi[i] = h16;
  g_xlo[i] = __float2bfloat16(v - __bfloat162float(h16));
}

// Zero parity-0 states (first NLAYER*HN elems of each array), 16B stores.
__global__ void zero_h() {
  const size_t nvec = (size_t)NLAYER * HN / 8;   // short8 vectors per array
  bf16x8s z = {};
  for (size_t i = (size_t)blockIdx.x * blockDim.x + threadIdx.x;
       i < nvec; i += (size_t)gridDim.x * blockDim.x) {
    ((bf16x8s*)g_h_hi)[i] = z;
    ((bf16x8s*)g_h_lo)[i] = z;
  }
}

__global__ void init_ctrl() {
  if (threadIdx.x == 0) { g_ctrl.done = 0u; g_ctrl.t_conv = MAXT; }
  if (threadIdx.x < MAXT) g_ctrl.delta[threadIdx.x] = 0u;
}

// -------------------------------------------------------- fused GEMM + state
// m97-structure: 128x128 tile, BK=64, 4 waves (2x2), global_load_lds(16B),
// 2-barrier K loop, MFMA 16x16x32 bf16. Epilogue is register-local.
__launch_bounds__(256, 2)
__global__ void fused_step(int layer, int pin, int pout, int t) {
  if (g_ctrl.done) return;   // frozen after convergence (uniform, all exit)

  const __hip_bfloat16* cur_hi  = (layer == 0) ? g_xhi : &g_h_hi[((size_t)pout * NLAYER + (layer - 1)) * HN];
  const __hip_bfloat16* cur_lo  = (layer == 0) ? g_xlo : &g_h_lo[((size_t)pout * NLAYER + (layer - 1)) * HN];
  const __hip_bfloat16* h_hi_in = &g_h_hi[((size_t)pin * NLAYER + layer) * HN];
  const __hip_bfloat16* h_lo_in = &g_h_lo[((size_t)pin * NLAYER + layer) * HN];
  __hip_bfloat16* h_hi_out      = &g_h_hi[((size_t)pout * NLAYER + layer) * HN];
  __hip_bfloat16* h_lo_out      = &g_h_lo[((size_t)pout * NLAYER + layer) * HN];
  const __hip_bfloat16* Wpl     = &g_Wp[(size_t)layer * WP_PER_LAYER];
  const float* btau  = &g_btau[layer * HD];
  const float* bforc = &g_bforc[layer * HD];

  __shared__ __align__(16) __hip_bfloat16 Asm[128 * 64];  // [m][k]
  __shared__ __align__(16) __hip_bfloat16 Bsm[128 * 64];  // [n][k]

  const int tid  = threadIdx.x;
  const int lane = tid & 63;
  const int wave = tid >> 6;
  const int wm = wave >> 1, wn = wave & 1;
  const int m0 = blockIdx.x * 128;
  const int nt = blockIdx.y;                 // 0..15

  f32x4 acc[4][4] = {};

  for (int kb = 0; kb < 6; ++kb) {
    const __hip_bfloat16* asrc;
    int sb;                                  // stored weight block for this pass
    switch (kb) {                            // uniform branch, 1 per 16 K-steps
      case 0: asrc = cur_hi;  sb = 0; break;
      case 1: asrc = h_hi_in; sb = 1; break;
      case 2: asrc = cur_lo;  sb = 0; break; // lo-A reuses hi weights
      case 3: asrc = h_lo_in; sb = 1; break;
      case 4: asrc = cur_hi;  sb = 2; break; // hi-A with lo weights
      default: asrc = h_hi_in; sb = 3; break;
    }
    for (int t16 = 0; t16 < 16; ++t16) {
      const int kts = sb * 16 + t16;         // storage k-tile index 0..63
      const int kcol = t16 * 64;
      // stage A: 16 x 1KB wave-chunks, 8 rows each; LDS linear [m][64].
      // lane l of chunk g: row g*8+(l>>3), k-group (l&7)*8 -> LDS elem g*512+l*8.
      #pragma unroll
      for (int i = 0; i < 4; ++i) {
        int g = wave * 4 + i;
        int row = g * 8 + (lane >> 3);
        gload_lds16(asrc + (size_t)(m0 + row) * HD + kcol + (lane & 7) * 8,
                    &Asm[g * 512]);
      }
      // stage B: contiguous pre-packed 16KB tile (identity copy)
      const __hip_bfloat16* bp = Wpl + ((size_t)kts * 16 + nt) * 8192;
      #pragma unroll
      for (int i = 0; i < 4; ++i) {
        int g = wave * 4 + i;
        gload_lds16(bp + g * 512 + lane * 8, &Bsm[g * 512]);
      }
      __syncthreads();
      #pragma unroll
      for (int ks = 0; ks < 2; ++ks) {
        const int k0 = ks * 32 + (lane >> 4) * 8;
        bf16x8s af[4], bfr[4];
        #pragma unroll
        for (int fm = 0; fm < 4; ++fm)
          af[fm] = *(const bf16x8s*)&Asm[(wm * 64 + fm * 16 + (lane & 15)) * 64 + k0];
        #pragma unroll
        for (int fn = 0; fn < 4; ++fn)
          bfr[fn] = *(const bf16x8s*)&Bsm[(wn * 64 + fn * 16 + (lane & 15)) * 64 + k0];
        #pragma unroll
        for (int fm = 0; fm < 4; ++fm)
          #pragma unroll
          for (int fn = 0; fn < 4; ++fn)
            acc[fm][fn] = __builtin_amdgcn_mfma_f32_16x16x32_bf16(
                af[fm], bfr[fn], acc[fm][fn], 0, 0, 0);
      }
      __syncthreads();
    }
  }

  // ---- epilogue: C/D frag (row=(lane>>4)*4+r, col=lane&15); fn even=tau,
  // fn odd=forc for the SAME j -> thread-local pairing.
  // j for fn=2p or 2p+1: (nt*4 + wn*2 + p)*16 + col.
  float lmax = 0.0f;
  const int col = lane & 15;
  const int rbase = (lane >> 4) * 4;
  #pragma unroll
  for (int fm = 0; fm < 4; ++fm) {
    #pragma unroll
    for (int p = 0; p < 2; ++p) {
      const int j = nt * 64 + wn * 32 + p * 16 + col;
      const float bt = btau[j], bfo = bforc[j];
      f32x4 tp = acc[fm][2 * p];
      f32x4 fp = acc[fm][2 * p + 1];
      #pragma unroll
      for (int r2 = 0; r2 < 4; ++r2) {
        const int m = m0 + wm * 64 + fm * 16 + rbase + r2;
        const size_t off = (size_t)m * HD + j;
        // stable_sigmoid(v) = 0.5*(tanh(v/2)+1)
        float tau  = 0.5f * (fast_tanh(0.5f * (tp[r2] + bt)) + 1.0f);
        float forc = fast_tanh(fp[r2] + bfo);
        float hold = __bfloat162float(h_hi_in[off]) + __bfloat162float(h_lo_in[off]);
        float hn = hold + DTC * (-hold / (tau + EPS_TAU_C) + forc);
        hn = fminf(10.0f, fmaxf(-10.0f, hn));
        lmax = fmaxf(lmax, fabsf(hn - hold));
        __hip_bfloat16 hhi = __float2bfloat16(hn);
        h_hi_out[off] = hhi;
        h_lo_out[off] = __float2bfloat16(hn - __bfloat162float(hhi));
      }
    }
  }
  #pragma unroll
  for (int s = 32; s; s >>= 1) lmax = fmaxf(lmax, __shfl_xor(lmax, s, 64));
  if (lane == 0) atomicMax(&g_ctrl.delta[t], __float_as_uint(lmax));
}

__global__ void check_step(int t) {
  if (threadIdx.x != 0) return;
  if (g_ctrl.done) return;
  if (__uint_as_float(g_ctrl.delta[t]) < EPS_CONV_C) { g_ctrl.done = 1u; g_ctrl.t_conv = t; }
}

__global__ void write_out(float* __restrict__ out, int out_size) {
  size_t i = (size_t)blockIdx.x * blockDim.x + threadIdx.x;
  if (i >= (size_t)out_size) return;
  int tc = g_ctrl.t_conv;
  int last = (tc >= MAXT) ? (MAXT - 1) : tc;
  int par = (last + 1) & 1;                  // parity buffer holding final state
  const __hip_bfloat16* hh = &g_h_hi[((size_t)par * NLAYER + (NLAYER - 1)) * HN];
  const __hip_bfloat16* hl = &g_h_lo[((size_t)par * NLAYER + (NLAYER - 1)) * HN];
  if (i == (size_t)(out_size - 1)) {
    out[i] = (float)tc;                      // t_conv (float-promoted concat)
  } else if (i < HN) {
    out[i] = __bfloat162float(hh[i]) + __bfloat162float(hl[i]);
  }
}

// -------------------------------------------------------------------- launch
extern "C" void kernel_launch(void* const* d_in, const int* in_sizes, int n_in,
                              void* d_out, int out_size, void* d_ws, size_t ws_size,
                              hipStream_t stream) {
  const float* x       = (const float*)d_in[0];
  const float* w_state = (const float*)d_in[1];
  const float* b_state = (const float*)d_in[2];
  const float* w_input = (const float*)d_in[3];
  const float* b_input = (const float*)d_in[4];
  const float* w_tau   = (const float*)d_in[5];
  const float* b_tau   = (const float*)d_in[6];
  (void)d_ws; (void)ws_size; (void)in_sizes; (void)n_in;

  // prep (graph-captured, reruns every call; all static buffers fully rewritten)
  {
    size_t total = (size_t)NLAYER * KSTORE * NPACK;
    pack_weights<<<dim3((unsigned)((total + 255) / 256)), dim3(256), 0, stream>>>(
        w_state, w_input, w_tau, b_state, b_input, b_tau);
  }
  split_x<<<dim3((unsigned)((HN + 255) / 256)), dim3(256), 0, stream>>>(x);
  zero_h<<<dim3(2048), dim3(256), 0, stream>>>();
  init_ctrl<<<dim3(1), dim3(64), 0, stream>>>();

  for (int t = 0; t < MAXT; ++t) {
    const int pin = t & 1, pout = 1 - pin;
    for (int l = 0; l < NLAYER; ++l) {
      fused_step<<<dim3(64, 16), dim3(256), 0, stream>>>(l, pin, pout, t);
    }
    check_step<<<dim3(1), dim3(64), 0, stream>>>(t);
  }

  write_out<<<dim3((unsigned)((HN + 256) / 256)), dim3(256), 0, stream>>>(
      (float*)d_out, out_size);
}

// Round 6
// 47178.906 us; speedup vs baseline: 1.4915x; 1.4915x over previous
//
#include <hip/hip_runtime.h>
#include <hip/hip_bf16.h>

// ContinuousRecurrentCore (liquid-time-constant net) on MI355X.
//
// Per (step,layer): ONE fused MFMA GEMM producing both tau_pre and
// forcing_pre, + register-local epilogue (sigmoid/tanh/state update/delta max).
// R6 numerics: A (x,h) kept in fp32 precision via bf16 hi/lo split;
// W quantized to bf16 (hi only). A*W = (Ahi+Alo)*Whi -> 4 passes over
// 2 stored weight K-blocks, K_eff = 4096. Error = deterministic bf16
// weight quantization only (R5 anchor with W-correction passes: absmax
// 2.44e-4; predicted here ~5e-4-2e-3).
// N=2048 packs tau/forc columns in alternating 16-wide blocks so each
// thread's MFMA C-fragments hold matching (tau, forc) pairs for the same
// output element -> no cross-lane epilogue.
// Device-side early-exit preserves reference freeze/t_conv semantics.
// All buffers in static __device__ globals (R4 d_ws-overflow crash fix).

typedef __attribute__((ext_vector_type(8))) short bf16x8s;
typedef __attribute__((ext_vector_type(4))) float f32x4;

constexpr int HD = 1024;       // hidden dim
constexpr int MR = 8192;       // B*S rows
constexpr int NLAYER = 4;
constexpr int MAXT = 50;
constexpr float DTC = 0.05f;
constexpr float EPS_TAU_C = 1e-6f;
constexpr float EPS_CONV_C = 1e-3f;

// packed GEMM dims
constexpr int KSTORE = 2048;   // 2 stored K-blocks of 1024: [Wx_hi, Wh_hi]
constexpr int NPACK = 2048;    // tau/forc interleaved at 16-col granularity
constexpr size_t WP_PER_LAYER = (size_t)(KSTORE / 64) * 16 * 128 * 64;  // 4.19M elem
constexpr size_t HN = (size_t)MR * HD;      // elements in one state array

struct Ctrl {
  unsigned int done;
  int t_conv;
  unsigned int delta[MAXT];
};

// ---------------------------------------------------------- static workspace
__device__ __align__(16) __hip_bfloat16 g_Wp[NLAYER * WP_PER_LAYER];   // 33.5MB
__device__ __align__(16) __hip_bfloat16 g_xhi[HN];                     // 16.8MB
__device__ __align__(16) __hip_bfloat16 g_xlo[HN];                     // 16.8MB
__device__ __align__(16) __hip_bfloat16 g_h_hi[2 * NLAYER * HN];       // 134MB [par][layer][elem]
__device__ __align__(16) __hip_bfloat16 g_h_lo[2 * NLAYER * HN];       // 134MB
__device__ float g_btau[NLAYER * HD];
__device__ float g_bforc[NLAYER * HD];
__device__ Ctrl g_ctrl;

__device__ __forceinline__ void gload_lds16(const __hip_bfloat16* g, __hip_bfloat16* lds) {
  __builtin_amdgcn_global_load_lds(
      (const __attribute__((address_space(1))) unsigned int*)g,
      (__attribute__((address_space(3))) unsigned int*)lds, 16, 0, 0);
}

// Branch-free tanh: t = e^{-2|x|} in (0,1] (never overflows),
// tanh = sign(x)*(1-t)/(1+t). ~1e-6 abs error, well below the GEMM
// weight-quantization error (~7e-4 preact) that bounds trajectory fidelity.
__device__ __forceinline__ float fast_tanh(float x) {
  float t = __expf(-2.0f * fabsf(x));
  float r = __fdividef(1.0f - t, 1.0f + t);
  return copysignf(r, x);
}

// ---------------------------------------------------------------- weight pack
// g_Wp layout: [layer][kt(32)][nt(16)][nn(128)][kk(64)] bf16 — B-tiles are
// contiguous 16KB blobs, LDS image is [n][k] (k contiguous per column).
// n-packing: b=n>>4 (16-col blocks), j=(b>>1)*16+(n&15); b even=tau, odd=forc.
// k-storage: kb=kg>>10 -> [Wx_hi, Wh_hi].
// GEMM runs 4 passes pairing (A-source, stored block):
//   p0:(x_hi,Wx_hi) p1:(h_hi,Wh_hi) p2:(x_lo,Wx_hi) p3:(h_lo,Wh_hi)
//   -> A at fp32 precision, W at bf16.
__global__ void pack_weights(const float* __restrict__ w_state,
                             const float* __restrict__ w_input,
                             const float* __restrict__ w_tau,
                             const float* __restrict__ b_state,
                             const float* __restrict__ b_input,
                             const float* __restrict__ b_tau) {
  size_t idx = (size_t)blockIdx.x * blockDim.x + threadIdx.x;
  if (idx < (size_t)NLAYER * HD) {
    int l = (int)(idx >> 10), jj = (int)(idx & 1023);
    g_btau[idx]  = b_tau[l * HD + jj];
    g_bforc[idx] = b_state[l * HD + jj] + b_input[l * HD + jj];
  }
  const size_t total = (size_t)NLAYER * KSTORE * NPACK;
  if (idx >= total) return;
  int kk = (int)(idx & 63);  size_t r = idx >> 6;
  int nn = (int)(r & 127);   r >>= 7;
  int nt = (int)(r & 15);    r >>= 4;
  int kt = (int)(r & 31);    // KSTORE/64 = 32 k-tiles
  int layer = (int)(r >> 5);
  int kg = kt * 64 + kk;
  int kb = kg >> 10;         // 0..1 stored blocks
  int k  = kg & 1023;
  int n  = nt * 128 + nn;
  int b  = n >> 4;
  int j  = (b >> 1) * 16 + (n & 15);
  bool is_tau = (b & 1) == 0;
  bool is_h   = (kb & 1) != 0;
  float wv;
  if (is_tau) wv = w_tau[(size_t)layer * HD * 2 * HD + (size_t)j * 2 * HD + (is_h ? HD + k : k)];
  else        wv = is_h ? w_state[(size_t)layer * HD * HD + (size_t)j * HD + k]
                        : w_input[(size_t)layer * HD * HD + (size_t)j * HD + k];
  g_Wp[idx] = __float2bfloat16(wv);
}

// ------------------------------------------------------------------- x split
__global__ void split_x(const float* __restrict__ x) {
  size_t i = (size_t)blockIdx.x * blockDim.x + threadIdx.x;
  if (i >= HN) return;
  float v = x[i];
  __hip_bfloat16 h16 = __float2bfloat16(v);
  g_xhi[i] = h16;
  g_xlo[i] = __float2bfloat16(v - __bfloat162float(h16));
}

// Zero parity-0 states (first NLAYER*HN elems of each array), 16B stores.
__global__ void zero_h() {
  const size_t nvec = (size_t)NLAYER * HN / 8;   // short8 vectors per array
  bf16x8s z = {};
  for (size_t i = (size_t)blockIdx.x * blockDim.x + threadIdx.x;
       i < nvec; i += (size_t)gridDim.x * blockDim.x) {
    ((bf16x8s*)g_h_hi)[i] = z;
    ((bf16x8s*)g_h_lo)[i] = z;
  }
}

__global__ void init_ctrl() {
  if (threadIdx.x == 0) { g_ctrl.done = 0u; g_ctrl.t_conv = MAXT; }
  if (threadIdx.x < MAXT) g_ctrl.delta[threadIdx.x] = 0u;
}

// -------------------------------------------------------- fused GEMM + state
// m97-structure: 128x128 tile, BK=64, 4 waves (2x2), global_load_lds(16B),
// 2-barrier K loop, MFMA 16x16x32 bf16. Epilogue is register-local.
__launch_bounds__(256, 2)
__global__ void fused_step(int layer, int pin, int pout, int t) {
  if (g_ctrl.done) return;   // frozen after convergence (uniform, all exit)

  const __hip_bfloat16* cur_hi  = (layer == 0) ? g_xhi : &g_h_hi[((size_t)pout * NLAYER + (layer - 1)) * HN];
  const __hip_bfloat16* cur_lo  = (layer == 0) ? g_xlo : &g_h_lo[((size_t)pout * NLAYER + (layer - 1)) * HN];
  const __hip_bfloat16* h_hi_in = &g_h_hi[((size_t)pin * NLAYER + layer) * HN];
  const __hip_bfloat16* h_lo_in = &g_h_lo[((size_t)pin * NLAYER + layer) * HN];
  __hip_bfloat16* h_hi_out      = &g_h_hi[((size_t)pout * NLAYER + layer) * HN];
  __hip_bfloat16* h_lo_out      = &g_h_lo[((size_t)pout * NLAYER + layer) * HN];
  const __hip_bfloat16* Wpl     = &g_Wp[(size_t)layer * WP_PER_LAYER];
  const float* btau  = &g_btau[layer * HD];
  const float* bforc = &g_bforc[layer * HD];

  __shared__ __align__(16) __hip_bfloat16 Asm[128 * 64];  // [m][k]
  __shared__ __align__(16) __hip_bfloat16 Bsm[128 * 64];  // [n][k]

  const int tid  = threadIdx.x;
  const int lane = tid & 63;
  const int wave = tid >> 6;
  const int wm = wave >> 1, wn = wave & 1;
  const int m0 = blockIdx.x * 128;
  const int nt = blockIdx.y;                 // 0..15

  f32x4 acc[4][4] = {};

  for (int kb = 0; kb < 4; ++kb) {
    const __hip_bfloat16* asrc;
    int sb;                                  // stored weight block for this pass
    switch (kb) {                            // uniform branch, 1 per 16 K-steps
      case 0: asrc = cur_hi;  sb = 0; break;
      case 1: asrc = h_hi_in; sb = 1; break;
      case 2: asrc = cur_lo;  sb = 0; break; // lo-A reuses hi weights
      default: asrc = h_lo_in; sb = 1; break;
    }
    for (int t16 = 0; t16 < 16; ++t16) {
      const int kts = sb * 16 + t16;         // storage k-tile index 0..31
      const int kcol = t16 * 64;
      // stage A: 16 x 1KB wave-chunks, 8 rows each; LDS linear [m][64].
      // lane l of chunk g: row g*8+(l>>3), k-group (l&7)*8 -> LDS elem g*512+l*8.
      #pragma unroll
      for (int i = 0; i < 4; ++i) {
        int g = wave * 4 + i;
        int row = g * 8 + (lane >> 3);
        gload_lds16(asrc + (size_t)(m0 + row) * HD + kcol + (lane & 7) * 8,
                    &Asm[g * 512]);
      }
      // stage B: contiguous pre-packed 16KB tile (identity copy)
      const __hip_bfloat16* bp = Wpl + ((size_t)kts * 16 + nt) * 8192;
      #pragma unroll
      for (int i = 0; i < 4; ++i) {
        int g = wave * 4 + i;
        gload_lds16(bp + g * 512 + lane * 8, &Bsm[g * 512]);
      }
      __syncthreads();
      #pragma unroll
      for (int ks = 0; ks < 2; ++ks) {
        const int k0 = ks * 32 + (lane >> 4) * 8;
        bf16x8s af[4], bfr[4];
        #pragma unroll
        for (int fm = 0; fm < 4; ++fm)
          af[fm] = *(const bf16x8s*)&Asm[(wm * 64 + fm * 16 + (lane & 15)) * 64 + k0];
        #pragma unroll
        for (int fn = 0; fn < 4; ++fn)
          bfr[fn] = *(const bf16x8s*)&Bsm[(wn * 64 + fn * 16 + (lane & 15)) * 64 + k0];
        #pragma unroll
        for (int fm = 0; fm < 4; ++fm)
          #pragma unroll
          for (int fn = 0; fn < 4; ++fn)
            acc[fm][fn] = __builtin_amdgcn_mfma_f32_16x16x32_bf16(
                af[fm], bfr[fn], acc[fm][fn], 0, 0, 0);
      }
      __syncthreads();
    }
  }

  // ---- epilogue: C/D frag (row=(lane>>4)*4+r, col=lane&15); fn even=tau,
  // fn odd=forc for the SAME j -> thread-local pairing.
  // j for fn=2p or 2p+1: (nt*4 + wn*2 + p)*16 + col.
  float lmax = 0.0f;
  const int col = lane & 15;
  const int rbase = (lane >> 4) * 4;
  #pragma unroll
  for (int fm = 0; fm < 4; ++fm) {
    #pragma unroll
    for (int p = 0; p < 2; ++p) {
      const int j = nt * 64 + wn * 32 + p * 16 + col;
      const float bt = btau[j], bfo = bforc[j];
      f32x4 tp = acc[fm][2 * p];
      f32x4 fp = acc[fm][2 * p + 1];
      #pragma unroll
      for (int r2 = 0; r2 < 4; ++r2) {
        const int m = m0 + wm * 64 + fm * 16 + rbase + r2;
        const size_t off = (size_t)m * HD + j;
        // stable_sigmoid(v) = 0.5*(tanh(v/2)+1)
        float tau  = 0.5f * (fast_tanh(0.5f * (tp[r2] + bt)) + 1.0f);
        float forc = fast_tanh(fp[r2] + bfo);
        float hold = __bfloat162float(h_hi_in[off]) + __bfloat162float(h_lo_in[off]);
        float hn = hold + DTC * (-hold / (tau + EPS_TAU_C) + forc);
        hn = fminf(10.0f, fmaxf(-10.0f, hn));
        lmax = fmaxf(lmax, fabsf(hn - hold));
        __hip_bfloat16 hhi = __float2bfloat16(hn);
        h_hi_out[off] = hhi;
        h_lo_out[off] = __float2bfloat16(hn - __bfloat162float(hhi));
      }
    }
  }
  #pragma unroll
  for (int s = 32; s; s >>= 1) lmax = fmaxf(lmax, __shfl_xor(lmax, s, 64));
  if (lane == 0) atomicMax(&g_ctrl.delta[t], __float_as_uint(lmax));
}

__global__ void check_step(int t) {
  if (threadIdx.x != 0) return;
  if (g_ctrl.done) return;
  if (__uint_as_float(g_ctrl.delta[t]) < EPS_CONV_C) { g_ctrl.done = 1u; g_ctrl.t_conv = t; }
}

__global__ void write_out(float* __restrict__ out, int out_size) {
  size_t i = (size_t)blockIdx.x * blockDim.x + threadIdx.x;
  if (i >= (size_t)out_size) return;
  int tc = g_ctrl.t_conv;
  int last = (tc >= MAXT) ? (MAXT - 1) : tc;
  int par = (last + 1) & 1;                  // parity buffer holding final state
  const __hip_bfloat16* hh = &g_h_hi[((size_t)par * NLAYER + (NLAYER - 1)) * HN];
  const __hip_bfloat16* hl = &g_h_lo[((size_t)par * NLAYER + (NLAYER - 1)) * HN];
  if (i == (size_t)(out_size - 1)) {
    out[i] = (float)tc;                      // t_conv (float-promoted concat)
  } else if (i < HN) {
    out[i] = __bfloat162float(hh[i]) + __bfloat162float(hl[i]);
  }
}

// -------------------------------------------------------------------- launch
extern "C" void kernel_launch(void* const* d_in, const int* in_sizes, int n_in,
                              void* d_out, int out_size, void* d_ws, size_t ws_size,
                              hipStream_t stream) {
  const float* x       = (const float*)d_in[0];
  const float* w_state = (const float*)d_in[1];
  const float* b_state = (const float*)d_in[2];
  const float* w_input = (const float*)d_in[3];
  const float* b_input = (const float*)d_in[4];
  const float* w_tau   = (const float*)d_in[5];
  const float* b_tau   = (const float*)d_in[6];
  (void)d_ws; (void)ws_size; (void)in_sizes; (void)n_in;

  // prep (graph-captured, reruns every call; all static buffers fully rewritten)
  {
    size_t total = (size_t)NLAYER * KSTORE * NPACK;
    pack_weights<<<dim3((unsigned)((total + 255) / 256)), dim3(256), 0, stream>>>(
        w_state, w_input, w_tau, b_state, b_input, b_tau);
  }
  split_x<<<dim3((unsigned)((HN + 255) / 256)), dim3(256), 0, stream>>>(x);
  zero_h<<<dim3(2048), dim3(256), 0, stream>>>();
  init_ctrl<<<dim3(1), dim3(64), 0, stream>>>();

  for (int t = 0; t < MAXT; ++t) {
    const int pin = t & 1, pout = 1 - pin;
    for (int l = 0; l < NLAYER; ++l) {
      fused_step<<<dim3(64, 16), dim3(256), 0, stream>>>(l, pin, pout, t);
    }
    check_step<<<dim3(1), dim3(64), 0, stream>>>(t);
  }

  write_out<<<dim3((unsigned)((HN + 256) / 256)), dim3(256), 0, stream>>>(
      (float*)d_out, out_size);
}